// Round 1
// 317.455 us; speedup vs baseline: 1.1405x; 1.1405x over previous
//
#include <hip/hip_runtime.h>
#include <cstdint>
#include <cstddef>

// N=100000, E=300000, B=50000, L=4, D_EMB=128, D_HID=64, H=8. fp32 in/out.
// R4: fusion pass. k_P folded into k_dense epilogue (P from fp32 acc via
// shfl reductions); k_logits folded into k_scatter (8 lanes/edge);
// scan2+scan3 merged; count folded into prepW; 3 memsets -> 1;
// LDS-staged B-fragments in k_dense; online softmax in k_node_agg.
// Dispatches: 17 -> 11.

typedef __attribute__((ext_vector_type(8))) short bf16x8;
typedef __attribute__((ext_vector_type(4))) float f32x4;

__device__ __forceinline__ unsigned short f2bf(float f) {
    unsigned u = __float_as_uint(f);
    unsigned r = u + 0x7fffu + ((u >> 16) & 1u);
    return (unsigned short)(r >> 16);
}
__device__ __forceinline__ float bf2f(unsigned short h) {
    return __uint_as_float((unsigned)h << 16);
}

// ---------------------------------------------------------------------------
// Pack B = [Wi;Wp].T (K=128 x N=128) into MFMA B-frag order, split hi/lo bf16.
// pack[(s*8+c)*512 + L*8 + j] = B[k][n], k=s*32+(L>>4)*8+j, n=c*16+(L&15).
// Fused: batch-node multiplicity histogram (independent front-of-pipe work).
__global__ __launch_bounds__(256) void k_prep(
    const float* __restrict__ Wi, const float* __restrict__ Wp,
    unsigned short* __restrict__ Whi, unsigned short* __restrict__ Wlo,
    const int* __restrict__ batch_nodes, int* __restrict__ mult, int B) {
    int t = blockIdx.x * 256 + threadIdx.x;
    if (t < B) atomicAdd(&mult[batch_nodes[t]], 1);
    if (t >= 16384) return;
    int j = t & 7, L = (t >> 3) & 63, c = (t >> 9) & 7, s = t >> 12;
    int k = s * 32 + (L >> 4) * 8 + j;
    int n = c * 16 + (L & 15);
    float v = (n < 64) ? Wi[n * 128 + k] : Wp[(n - 64) * 128 + k];
    unsigned short h = f2bf(v);
    Whi[t] = h;
    Wlo[t] = f2bf(v - bf2f(h));
}

// ---------------------------------------------------------------------------
// Dense GEMM: Ybf[M x 128] = feat[M x 128] @ B, split-bf16 (3 MFMA per tile).
// Block = 4 waves; wave w does rows R0..R0+15, all 128 cols (8 col-tiles).
// B-fragments staged in LDS per k-step (16 KB) -> 4x less L2 traffic.
// Epilogue also emits P[n,16] = {Yi[n].attn_i, Yp[n].attn_i} from fp32 acc.
__global__ __launch_bounds__(256) void k_dense(
    const float* __restrict__ feat, const unsigned short* __restrict__ Whi,
    const unsigned short* __restrict__ Wlo, const float* __restrict__ attn,
    unsigned short* __restrict__ Ybf, float* __restrict__ P, int M) {
    __shared__ unsigned short sBh[4096];
    __shared__ unsigned short sBl[4096];
    int t = threadIdx.x;
    int wave = t >> 6;
    int L = t & 63;
    int m = L & 15, q = L >> 4;
    int R0 = blockIdx.x * 64 + wave * 16;

    f32x4 acc[8];
#pragma unroll
    for (int c = 0; c < 8; ++c) acc[c] = (f32x4){0.f, 0.f, 0.f, 0.f};

    int rowc = R0 + m; if (rowc > M - 1) rowc = M - 1;
    const float* arow = feat + (size_t)rowc * 128;

    for (int s = 0; s < 4; ++s) {
        __syncthreads();   // protect previous iteration's LDS reads
        {
            bf16x8* shp = (bf16x8*)sBh;
            bf16x8* slp = (bf16x8*)sBl;
            const bf16x8* gh = (const bf16x8*)(Whi + s * 4096);
            const bf16x8* gl = (const bf16x8*)(Wlo + s * 4096);
            shp[t] = gh[t]; shp[t + 256] = gh[t + 256];
            slp[t] = gl[t]; slp[t + 256] = gl[t + 256];
        }
        __syncthreads();

        const float4* ap = (const float4*)(arow + s * 32 + q * 8);
        float4 a0 = ap[0], a1 = ap[1];
        float av[8] = {a0.x, a0.y, a0.z, a0.w, a1.x, a1.y, a1.z, a1.w};
        bf16x8 ahi, alo;
#pragma unroll
        for (int j = 0; j < 8; ++j) {
            unsigned short h = f2bf(av[j]);
            ahi[j] = (short)h;
            alo[j] = (short)f2bf(av[j] - bf2f(h));
        }
#pragma unroll
        for (int c = 0; c < 8; ++c) {
            const bf16x8 bh = *(const bf16x8*)(sBh + c * 512 + L * 8);
            const bf16x8 bl = *(const bf16x8*)(sBl + c * 512 + L * 8);
            acc[c] = __builtin_amdgcn_mfma_f32_16x16x32_bf16(ahi, bh, acc[c], 0, 0, 0);
            acc[c] = __builtin_amdgcn_mfma_f32_16x16x32_bf16(ahi, bl, acc[c], 0, 0, 0);
            acc[c] = __builtin_amdgcn_mfma_f32_16x16x32_bf16(alo, bh, acc[c], 0, 0, 0);
        }
    }
    // C/D layout: col = lane&15 (=m), row = (lane>>4)*4 + reg (=q*4+r)
#pragma unroll
    for (int c = 0; c < 8; ++c) {
#pragma unroll
        for (int r = 0; r < 4; ++r) {
            int row = R0 + q * 4 + r;
            if (row < M) Ybf[(size_t)row * 128 + c * 16 + m] = f2bf(acc[c][r]);
        }
    }
    // P epilogue: P[row,i] = Yi[row].attn_i, P[row,8+i] = Yp[row].attn_i.
    // Lane (q,m) holds cols c*16+m of rows q*4+r; reduce over m (16-lane group).
#pragma unroll
    for (int i = 0; i < 8; ++i) {
        float a0 = attn[i * 64 + m];
        float a1 = attn[i * 64 + 16 + m];
        float a2 = attn[i * 64 + 32 + m];
        float a3 = attn[i * 64 + 48 + m];
#pragma unroll
        for (int r = 0; r < 4; ++r) {
            int row = R0 + q * 4 + r;
            float pi = acc[0][r] * a0 + acc[1][r] * a1 + acc[2][r] * a2 + acc[3][r] * a3;
            float pp = acc[4][r] * a0 + acc[5][r] * a1 + acc[6][r] * a2 + acc[7][r] * a3;
#pragma unroll
            for (int o = 1; o < 16; o <<= 1) {
                pi += __shfl_xor(pi, o);
                pp += __shfl_xor(pp, o);
            }
            if (row < M) {
                if (m == i)     P[(size_t)row * 16 + i] = pi;
                if (m == i + 8) P[(size_t)row * 16 + 8 + i] = pp;
            }
        }
    }
}

// ---------------------------------------------------------------------------
// count[d] = #incoming edges for flagged d
__global__ __launch_bounds__(256) void k_hist(
    const int* __restrict__ edge_dst, const int* __restrict__ mult,
    int* __restrict__ count, int E) {
    int e = blockIdx.x * 256 + threadIdx.x;
    if (e >= E) return;
    int d = edge_dst[e];
    if (mult[d] > 0) atomicAdd(&count[d], 1);
}

// per-block exclusive scan of count + block partial sums
__global__ __launch_bounds__(256) void k_scan1(
    const int* __restrict__ count, int* __restrict__ excl, int* __restrict__ partials, int N) {
    __shared__ int lds[256];
    int t = threadIdx.x, i = blockIdx.x * 256 + t;
    int c = (i < N) ? count[i] : 0;
    lds[t] = c; __syncthreads();
    for (int o = 1; o < 256; o <<= 1) {
        int v = (t >= o) ? lds[t - o] : 0;
        __syncthreads(); lds[t] += v; __syncthreads();
    }
    if (i < N) excl[i] = lds[t] - c;
    if (t == 255) partials[blockIdx.x] = lds[255];
}

// merged scan2+scan3: each block reduces partials[0..bid) itself (<=512 ints),
// then writes offsets/cursor; last block also writes offsets[N] = Ec.
__global__ __launch_bounds__(256) void k_scan23(
    const int* __restrict__ excl, const int* __restrict__ partials,
    int* __restrict__ offsets, int* __restrict__ cursor, int N) {
    __shared__ int sacc[256];
    int bid = blockIdx.x, t = threadIdx.x;
    int s = 0;
    for (int j = t; j < bid; j += 256) s += partials[j];
    sacc[t] = s; __syncthreads();
#pragma unroll
    for (int o = 128; o > 0; o >>= 1) {
        if (t < o) sacc[t] += sacc[t + o];
        __syncthreads();
    }
    int boff = sacc[0];
    int i = bid * 256 + t;
    if (i < N) {
        int o = excl[i] + boff;
        offsets[i] = o; cursor[i] = o;
    }
    if (t == 0 && bid == gridDim.x - 1) offsets[N] = boff + partials[bid];
}

// ---------------------------------------------------------------------------
// Fused scatter + logits: 8 lanes per edge (h = lane&7). Lane 0 claims the
// csr slot via atomic cursor, broadcasts pos; all lanes compute talking-heads
// logits directly into logits[pos], mpc[pos]. csr array eliminated.
__global__ __launch_bounds__(256) void k_scatter_logits(
    const int* __restrict__ edge_dst, const int* __restrict__ mult,
    int* __restrict__ cursor, const int* __restrict__ mp,
    const float* __restrict__ P, const float* __restrict__ Wth,
    float* __restrict__ logits, int4* __restrict__ mpc, int E) {
    int e = blockIdx.x * 32 + (threadIdx.x >> 3);
    if (e >= E) return;
    int h = threadIdx.x & 7;
    int d = edge_dst[e];
    if (mult[d] == 0) return;
    int pos = 0;
    if (h == 0) pos = atomicAdd(&cursor[d], 1);
    int gbase = threadIdx.x & ~7;
    pos = __shfl(pos, gbase);
    int4 rows = *(const int4*)(mp + (size_t)e * 4);
    float s = P[(size_t)rows.x * 16 + h] + P[(size_t)rows.w * 16 + h]
            + P[(size_t)rows.y * 16 + 8 + h] + P[(size_t)rows.z * 16 + 8 + h];
    float l = 0.f;
#pragma unroll
    for (int j = 0; j < 8; ++j) {
        float sj = __shfl(s, gbase + j);
        l += Wth[h * 8 + j] * sj;
    }
    l = l > 0.f ? l : 0.01f * l;
    logits[(size_t)pos * 8 + h] = l;
    if (h == 0) mpc[pos] = rows;
}

// ---------------------------------------------------------------------------
// Per flagged node: single-pass ONLINE softmax + aggregation from Ybf.
// One wave per node, lane = d. Writes nftb (bf16) once; fused gate dot.
__global__ __launch_bounds__(256) void k_node_agg(
    const unsigned short* __restrict__ Ybf, const float* __restrict__ logits,
    const int4* __restrict__ mpc, const int* __restrict__ offsets,
    const int* __restrict__ mult, const float* __restrict__ Wg,
    unsigned short* __restrict__ nftb, float* __restrict__ gate_part, int N) {
    int n = blockIdx.x * 4 + (threadIdx.x >> 6);
    int lane = threadIdx.x & 63;
    if (n >= N) return;
    int m = mult[n];
    if (m == 0) return;
    int beg = offsets[n], end = offsets[n + 1];

    float mx[8], den[8], acc[8];
#pragma unroll
    for (int h = 0; h < 8; ++h) { mx[h] = -1e30f; den[h] = 0.f; acc[h] = 0.f; }

    for (int j = beg; j < end; ++j) {
        const float4* lp = (const float4*)(logits + (size_t)j * 8);
        float4 l0 = lp[0], l1 = lp[1];
        int4 rows = mpc[j];
        float ed = bf2f(Ybf[(size_t)rows.x * 128 + lane])
                 + bf2f(Ybf[(size_t)rows.w * 128 + lane])
                 + bf2f(Ybf[(size_t)rows.y * 128 + 64 + lane])
                 + bf2f(Ybf[(size_t)rows.z * 128 + 64 + lane]);
#define OSM_STEP(H, LV)                                            \
        {                                                          \
            float nm = fmaxf(mx[H], (LV));                         \
            float cr = __expf(mx[H] - nm);                         \
            float w  = __expf((LV) - nm);                          \
            den[H] = den[H] * cr + w;                              \
            acc[H] = acc[H] * cr + w * ed;                         \
            mx[H] = nm;                                            \
        }
        OSM_STEP(0, l0.x) OSM_STEP(1, l0.y) OSM_STEP(2, l0.z) OSM_STEP(3, l0.w)
        OSM_STEP(4, l1.x) OSM_STEP(5, l1.y) OSM_STEP(6, l1.z) OSM_STEP(7, l1.w)
#undef OSM_STEP
    }
#pragma unroll
    for (int h = 0; h < 8; ++h) {
        float r = (end > beg) ? 1.f / den[h] : 0.f;
        acc[h] *= r;
    }

    unsigned short* base = nftb + (size_t)n * 512;
#pragma unroll
    for (int h = 0; h < 8; ++h) base[h * 64 + lane] = f2bf(acc[h]);

    float wg = Wg[lane];
    float myg = 0.f;
#pragma unroll
    for (int h = 0; h < 8; ++h) {
        float p = acc[h] * wg;
#pragma unroll
        for (int o = 32; o > 0; o >>= 1) p += __shfl_xor(p, o);
        if (lane == h) myg = p;
    }
    if (lane < 8)
        atomicAdd(&gate_part[(blockIdx.x & 1023) * 8 + lane], (float)m * myg);
}

// gate[h] = sum(gate_part)/B + b_gate
__global__ __launch_bounds__(256) void k_gatefinal(
    const float* __restrict__ gate_part, const float* __restrict__ b_gate,
    float* __restrict__ gate, int B) {
    __shared__ float lds[256];
    int t = threadIdx.x;
    int h = t & 7, g = t >> 3;
    float s = 0.f;
    for (int b = g; b < 1024; b += 32) s += gate_part[b * 8 + h];
    lds[t] = s; __syncthreads();
    if (t < 8) {
        float tot = 0.f;
        for (int gg = 0; gg < 32; ++gg) tot += lds[gg * 8 + t];
        gate[t] = tot / (float)B + b_gate[0];
    }
}

// out[b, h*64+d] = nftb[batch_nodes[b]] * gate[h]
__global__ __launch_bounds__(256) void k_output(
    const unsigned short* __restrict__ nftb, const int* __restrict__ batch_nodes,
    const float* __restrict__ gate, float* __restrict__ out, int B) {
    int idx = blockIdx.x * 256 + threadIdx.x;
    int total = B * 128;
    if (idx >= total) return;
    int b = idx >> 7;
    int rem4 = idx & 127;
    int h = rem4 >> 4;
    int n = batch_nodes[b];
    ushort4 v = *(const ushort4*)(nftb + (size_t)n * 512 + rem4 * 4);
    float g = gate[h];
    float4 o;
    o.x = bf2f(v.x) * g; o.y = bf2f(v.y) * g;
    o.z = bf2f(v.z) * g; o.w = bf2f(v.w) * g;
    *(float4*)(out + (size_t)idx * 4) = o;
}

// ---------------------------------------------------------------------------
extern "C" void kernel_launch(void* const* d_in, const int* in_sizes, int n_in,
                              void* d_out, int out_size, void* d_ws, size_t ws_size,
                              hipStream_t stream) {
    const int*   batch_nodes = (const int*)d_in[0];
    const int*   mp          = (const int*)d_in[1];
    const int*   edge_dst    = (const int*)d_in[2];
    const float* feat        = (const float*)d_in[3];
    const float* W_i         = (const float*)d_in[4];
    const float* W_p         = (const float*)d_in[5];
    const float* attn        = (const float*)d_in[6];
    const float* W_th        = (const float*)d_in[7];
    const float* W_gate      = (const float*)d_in[8];
    const float* b_gate      = (const float*)d_in[9];
    float* out = (float*)d_out;

    const int B = in_sizes[0];
    const int E = in_sizes[2];
    const int N = in_sizes[3] / 128;
    const int nb_scan = (N + 255) / 256;

    char* w = (char*)d_ws;
    auto alloc = [&](size_t bytes) -> void* {
        void* p = (void*)w;
        w += (bytes + 255) & ~(size_t)255;
        return p;
    };
    unsigned short* Whi = (unsigned short*)alloc(16384 * 2);
    unsigned short* Wlo = (unsigned short*)alloc(16384 * 2);
    unsigned short* Ybf = (unsigned short*)alloc((size_t)N * 128 * 2);   // 25.6 MB
    float* P            = (float*)alloc((size_t)N * 16 * 4);             // 6.4 MB
    float* logits       = (float*)alloc((size_t)E * 8 * 4);              // 9.6 MB
    int4*  mpc          = (int4*)alloc((size_t)E * 16);                  // 4.8 MB
    // contiguous zero region: mult | count | gate_part  (single memset)
    size_t zero_bytes   = (size_t)N * 4 + (size_t)N * 4 + 1024 * 8 * 4;
    int*   mult         = (int*)alloc(zero_bytes);
    int*   count        = mult + N;
    float* gate_part    = (float*)(count + N);
    int*   excl         = (int*)alloc((size_t)N * 4);
    int*   offsets      = (int*)alloc((size_t)(N + 1) * 4);
    int*   cursor       = (int*)alloc((size_t)N * 4);
    int*   partials     = (int*)alloc(512 * 4);
    unsigned short* nftb = (unsigned short*)alloc((size_t)N * 512 * 2);  // 102.4 MB
    float* gate         = (float*)alloc(256);

    hipMemsetAsync(mult, 0, zero_bytes, stream);

    int prep_work = (B > 16384) ? B : 16384;
    k_prep<<<(prep_work + 255) / 256, 256, 0, stream>>>(W_i, W_p, Whi, Wlo,
                                                        batch_nodes, mult, B);
    k_dense<<<(N + 63) / 64, 256, 0, stream>>>(feat, Whi, Wlo, attn, Ybf, P, N);

    k_hist<<<(E + 255) / 256, 256, 0, stream>>>(edge_dst, mult, count, E);
    k_scan1<<<nb_scan, 256, 0, stream>>>(count, excl, partials, N);
    k_scan23<<<nb_scan, 256, 0, stream>>>(excl, partials, offsets, cursor, N);
    k_scatter_logits<<<(E + 31) / 32, 256, 0, stream>>>(edge_dst, mult, cursor,
                                                        mp, P, W_th, logits, mpc, E);
    k_node_agg<<<(N + 3) / 4, 256, 0, stream>>>(Ybf, logits, mpc, offsets, mult,
                                                W_gate, nftb, gate_part, N);
    k_gatefinal<<<1, 256, 0, stream>>>(gate_part, b_gate, gate, B);
    k_output<<<(B * 128 + 255) / 256, 256, 0, stream>>>(nftb, batch_nodes, gate, out, B);
}